// Round 1
// baseline (352.867 us; speedup 1.0000x reference)
//
#include <hip/hip_runtime.h>
#include <math.h>

#define NDET 512
#define NCLS 81
#define MM   784      // 28*28
#define PROBS_ELEMS (2 * NDET * MM)   // 802816
#define NMS_TH 0.5
#define EPS_D  1e-4

// ---------------- ws layout (bytes) ----------------
// 0      : double u[2][512]          (8192)
// 8192   : int order[512]            (2048)
// 16384  : u8 comp[2][512][512]      (524288)
// 540672 : u64 bits[2][512][8]       (65536)
// 606208 : u8 keepside[2][512]       (1024)
// total  : 607232 bytes

// K1: per (side, detection): gather label class, sigmoid (fp32, matches ref),
// write probs to d_out, fp64 row-sum -> u.
__global__ __launch_bounds__(256) void k1_gather_sigmoid(
    const float* __restrict__ left, const float* __restrict__ right,
    const int* __restrict__ labels, float* __restrict__ out,
    double* __restrict__ u) {
  int b = blockIdx.x;           // 0..1023
  int s = b >> 9;               // side
  int n = b & 511;              // detection
  const float* src = (s == 0) ? left : right;
  int lab = labels[n];
  const float4* in4 = (const float4*)(src + ((size_t)n * NCLS + lab) * MM);
  float4* out4 = (float4*)(out + ((size_t)s * NDET + n) * MM);
  int t = threadIdx.x;
  double local = 0.0;
  if (t < MM / 4) {             // 196 float4 per mask
    float4 v = in4[t];
    float4 r;
    r.x = 1.0f / (1.0f + expf(-v.x));
    r.y = 1.0f / (1.0f + expf(-v.y));
    r.z = 1.0f / (1.0f + expf(-v.z));
    r.w = 1.0f / (1.0f + expf(-v.w));
    out4[t] = r;
    local = (double)r.x + (double)r.y + (double)r.z + (double)r.w;
  }
  __shared__ double red[256];
  red[t] = local;
  __syncthreads();
  for (int st = 128; st > 0; st >>= 1) {
    if (t < st) red[t] += red[t + st];
    __syncthreads();
  }
  if (t == 0) u[s * NDET + n] = red[0];
}

// K2: single-block bitonic sort of 512 (score desc, idx asc) -> order[]
__global__ __launch_bounds__(512) void k2_sort(
    const float* __restrict__ scores, int* __restrict__ order) {
  __shared__ float sk[NDET];
  __shared__ int   si[NDET];
  int t = threadIdx.x;
  sk[t] = scores[t];
  si[t] = t;
  __syncthreads();
  for (int k = 2; k <= NDET; k <<= 1) {
    for (int j = k >> 1; j > 0; j >>= 1) {
      int p = t ^ j;
      if (p > t) {
        bool dir = ((t & k) == 0);   // descending block
        float sa = sk[t], sb = sk[p];
        int ia = si[t], ib = si[p];
        bool aBeforeB = (sa > sb) || (sa == sb && ia < ib);
        bool doSwap = dir ? (!aBeforeB) : aBeforeB;
        if (doSwap) { sk[t] = sb; si[t] = ib; sk[p] = sa; si[p] = ia; }
      }
      __syncthreads();
    }
  }
  order[t] = si[t];
}

// K3: upper-triangular 32x32 tiles of the sorted iou comparison matrix.
// comp[s][i][j] = (dot(P[o_i],P[o_j]) / (u[o_i]+EPS) >= 0.5), fp64 accumulate.
__global__ __launch_bounds__(256) void k3_iou_tiles(
    const float* __restrict__ P,        // d_out probs base (2*512*784 f32)
    const double* __restrict__ u,
    const int* __restrict__ order,
    unsigned char* __restrict__ comp) {
  int bi = blockIdx.x;                  // 0..271
  int s = bi / 136;
  int tri = bi % 136;
  int ti = 0, rem = tri;
  while (rem >= 16 - ti) { rem -= 16 - ti; ti++; }
  int tj = ti + rem;                    // tj >= ti

  __shared__ float As[32][112];
  __shared__ float Bs[32][112];
  __shared__ int oi[32], oj[32];
  __shared__ double den[32];

  int t = threadIdx.x;
  if (t < 32) {
    int r = order[ti * 32 + t];
    oi[t] = r;
    den[t] = u[s * NDET + r] + EPS_D;
    oj[t] = order[tj * 32 + t];
  }
  __syncthreads();

  const float* Pside = P + (size_t)s * NDET * MM;
  double acc[4] = {0.0, 0.0, 0.0, 0.0};
  int ty = t >> 5;        // 0..7
  int tx = t & 31;        // 0..31

  for (int kc = 0; kc < 7; kc++) {      // 7 * 112 = 784
    int k0 = kc * 112;
    for (int e = t; e < 32 * 112; e += 256) {
      int r = e / 112;
      int c = e - r * 112;
      As[r][c] = Pside[(size_t)oi[r] * MM + k0 + c];
      Bs[r][c] = Pside[(size_t)oj[r] * MM + k0 + c];
    }
    __syncthreads();
    for (int k = 0; k < 112; k++) {
      double b = (double)Bs[tx][k];
#pragma unroll
      for (int m = 0; m < 4; m++) {
        acc[m] += (double)As[ty + 8 * m][k] * b;
      }
    }
    __syncthreads();
  }

#pragma unroll
  for (int m = 0; m < 4; m++) {
    int y = ty + 8 * m;
    int i = ti * 32 + y;
    int j = tj * 32 + tx;
    double iou = acc[m] / den[y];
    comp[((size_t)s * NDET + i) * NDET + j] = (iou >= NMS_TH) ? 1 : 0;
  }
}

// K3b: pack comp bytes -> u64 bitmasks. word w = (s*512+i)*8+g covers bytes [64w, 64w+64)
__global__ __launch_bounds__(256) void k3b_pack(
    const unsigned char* __restrict__ comp,
    unsigned long long* __restrict__ bits) {
  int w = blockIdx.x * 256 + threadIdx.x;   // 0..8191
  if (w >= 2 * NDET * 8) return;
  const unsigned char* base = comp + (size_t)w * 64;
  unsigned long long v = 0ull;
#pragma unroll
  for (int L = 0; L < 64; L++) {
    v |= (unsigned long long)(base[L] & 1) << L;
  }
  bits[w] = v;
}

// K4: greedy suppression, one wave per side. Lane L holds bit g for column c=64g+L.
__global__ __launch_bounds__(64) void k4_greedy(
    const unsigned long long* __restrict__ bits,
    const int* __restrict__ order,
    unsigned char* __restrict__ keepside) {
  int s = blockIdx.x;
  int L = threadIdx.x;
  __shared__ unsigned long long B[NDET * 8];   // 32 KiB
  for (int e = L; e < NDET * 8; e += 64) B[e] = bits[(size_t)s * NDET * 8 + e];
  __syncthreads();

  unsigned long long sup = 0ull;
  for (int i = 0; i < NDET; i++) {
    int gi = i >> 6;
    int li = i & 63;
    unsigned int lo = (unsigned int)(sup & 0xffffffffull);
    unsigned int hi = (unsigned int)(sup >> 32);
    lo = __shfl(lo, li, 64);
    hi = __shfl(hi, li, 64);
    unsigned long long supli = ((unsigned long long)hi << 32) | (unsigned long long)lo;
    if (!((supli >> gi) & 1ull)) {       // row i active (wave-uniform branch)
#pragma unroll
      for (int g = 0; g < 8; g++) {
        unsigned long long w = B[i * 8 + g];
        unsigned long long bit = (w >> L) & 1ull;
        int c = (g << 6) | L;
        sup |= ((c > i) ? bit : 0ull) << g;
      }
    }
  }

#pragma unroll
  for (int g = 0; g < 8; g++) {
    int c = (g << 6) | L;
    int orig = order[c];
    keepside[s * NDET + orig] = (unsigned char)(((sup >> g) & 1ull) ^ 1ull);
  }
}

// K5: keep[n] = valid_l & valid_r & keepL & keepR -> float 0/1
__global__ __launch_bounds__(512) void k5_combine(
    const unsigned char* __restrict__ keepside,
    const double* __restrict__ u,
    float* __restrict__ outKeep) {
  int n = threadIdx.x;
  bool valid = (u[n] > 0.0) && (u[NDET + n] > 0.0);
  bool k = keepside[n] && keepside[NDET + n];
  outKeep[n] = (valid && k) ? 1.0f : 0.0f;
}

extern "C" void kernel_launch(void* const* d_in, const int* in_sizes, int n_in,
                              void* d_out, int out_size, void* d_ws, size_t ws_size,
                              hipStream_t stream) {
  const float* left   = (const float*)d_in[0];
  const float* right  = (const float*)d_in[1];
  const float* scores = (const float*)d_in[2];
  const int*   labels = (const int*)d_in[3];
  float* out = (float*)d_out;

  char* ws = (char*)d_ws;
  double* u                    = (double*)(ws + 0);
  int* order                   = (int*)(ws + 8192);
  unsigned char* comp          = (unsigned char*)(ws + 16384);
  unsigned long long* bits     = (unsigned long long*)(ws + 540672);
  unsigned char* keepside      = (unsigned char*)(ws + 606208);

  k1_gather_sigmoid<<<1024, 256, 0, stream>>>(left, right, labels, out, u);
  k2_sort<<<1, 512, 0, stream>>>(scores, order);
  k3_iou_tiles<<<272, 256, 0, stream>>>(out, u, order, comp);
  k3b_pack<<<32, 256, 0, stream>>>(comp, bits);
  k4_greedy<<<2, 64, 0, stream>>>(bits, order, keepside);
  k5_combine<<<1, 512, 0, stream>>>(keepside, u, out + PROBS_ELEMS);
}

// Round 2
// 306.841 us; speedup vs baseline: 1.1500x; 1.1500x over previous
//
#include <hip/hip_runtime.h>
#include <math.h>

#define NDET 512
#define NCLS 81
#define MM   784      // 28*28
#define PROBS_ELEMS (2 * NDET * MM)   // 802816
#define NMS_TH 0.5
#define EPS_D  1e-4
#define SD 114        // LDS row stride in floats: even (8B-aligned float2 rows),
                      // bank-pair stride 18 -> conflict-free for the 16-addr pattern

// ---------------- ws layout (bytes) ----------------
// 0      : double u[2][512]            (8192)
// 8192   : int order[512]              (2048)
// 16384  : u32 bits32[2][512][16]      (65536)   == u64 bits[2][512][8]
// total  : 81920 bytes

// K1: per (side, detection): gather label class, sigmoid (fp32, matches ref),
// write probs to d_out, fp64 row-sum -> u.
__global__ __launch_bounds__(256) void k1_gather_sigmoid(
    const float* __restrict__ left, const float* __restrict__ right,
    const int* __restrict__ labels, float* __restrict__ out,
    double* __restrict__ u) {
  int b = blockIdx.x;           // 0..1023
  int s = b >> 9;               // side
  int n = b & 511;              // detection
  const float* src = (s == 0) ? left : right;
  int lab = labels[n];
  const float4* in4 = (const float4*)(src + ((size_t)n * NCLS + lab) * MM);
  float4* out4 = (float4*)(out + ((size_t)s * NDET + n) * MM);
  int t = threadIdx.x;
  double local = 0.0;
  if (t < MM / 4) {             // 196 float4 per mask
    float4 v = in4[t];
    float4 r;
    r.x = 1.0f / (1.0f + expf(-v.x));
    r.y = 1.0f / (1.0f + expf(-v.y));
    r.z = 1.0f / (1.0f + expf(-v.z));
    r.w = 1.0f / (1.0f + expf(-v.w));
    out4[t] = r;
    local = (double)r.x + (double)r.y + (double)r.z + (double)r.w;
  }
  __shared__ double red[256];
  red[t] = local;
  __syncthreads();
  for (int st = 128; st > 0; st >>= 1) {
    if (t < st) red[t] += red[t + st];
    __syncthreads();
  }
  if (t == 0) u[s * NDET + n] = red[0];
}

// K2: single-block bitonic sort of 512 (score desc, idx asc) -> order[]
__global__ __launch_bounds__(512) void k2_sort(
    const float* __restrict__ scores, int* __restrict__ order) {
  __shared__ float sk[NDET];
  __shared__ int   si[NDET];
  int t = threadIdx.x;
  sk[t] = scores[t];
  si[t] = t;
  __syncthreads();
  for (int k = 2; k <= NDET; k <<= 1) {
    for (int j = k >> 1; j > 0; j >>= 1) {
      int p = t ^ j;
      if (p > t) {
        bool dir = ((t & k) == 0);   // descending block
        float sa = sk[t], sb = sk[p];
        int ia = si[t], ib = si[p];
        bool aBeforeB = (sa > sb) || (sa == sb && ia < ib);
        bool doSwap = dir ? (!aBeforeB) : aBeforeB;
        if (doSwap) { sk[t] = sb; si[t] = ib; sk[p] = sa; si[p] = ia; }
      }
      __syncthreads();
    }
  }
  order[t] = si[t];
}

// K3: upper-triangular 32x32 tiles of the sorted iou comparison matrix.
// 2x2 register tiling, float2 LDS reads, fp64 accumulate, ballot-packed
// 32-bit column-mask output (word tj of row i).
__global__ __launch_bounds__(256) void k3_iou(
    const float* __restrict__ P,        // d_out probs base (2*512*784 f32)
    const double* __restrict__ u,
    const int* __restrict__ order,
    unsigned int* __restrict__ bits32) {
  int bi = blockIdx.x;                  // 0..271
  int s = bi / 136;
  int tri = bi % 136;
  int ti = 0, rem = tri;
  while (rem >= 16 - ti) { rem -= 16 - ti; ti++; }
  int tj = ti + rem;                    // tj >= ti

  __shared__ __align__(16) float As[32][SD];
  __shared__ __align__(16) float Bs[32][SD];
  __shared__ int oi[32], oj[32];
  __shared__ double den[32];

  int t = threadIdx.x;
  if (t < 32) {
    int r = order[ti * 32 + t];
    oi[t] = r;
    den[t] = u[s * NDET + r] + EPS_D;
    oj[t] = order[tj * 32 + t];
  }
  __syncthreads();

  const float* Pside = P + (size_t)s * NDET * MM;
  int cx = t & 15;          // column sub-index (fastest-varying within wave)
  int ry = t >> 4;          // row sub-index 0..15
  double a00 = 0.0, a01 = 0.0, a10 = 0.0, a11 = 0.0;

  for (int kc = 0; kc < 7; kc++) {      // 7 * 112 = 784
    int k0 = kc * 112;
    for (int e = t; e < 32 * 112; e += 256) {
      int r = e / 112;
      int c = e - r * 112;
      As[r][c] = Pside[(size_t)oi[r] * MM + k0 + c];
      Bs[r][c] = Pside[(size_t)oj[r] * MM + k0 + c];
    }
    __syncthreads();
    for (int kp = 0; kp < 56; kp++) {
      float2 fa0 = *(const float2*)&As[ry][2 * kp];
      float2 fa1 = *(const float2*)&As[ry + 16][2 * kp];
      float2 fb0 = *(const float2*)&Bs[cx][2 * kp];
      float2 fb1 = *(const float2*)&Bs[cx + 16][2 * kp];
      a00 += (double)fa0.x * (double)fb0.x; a00 += (double)fa0.y * (double)fb0.y;
      a01 += (double)fa0.x * (double)fb1.x; a01 += (double)fa0.y * (double)fb1.y;
      a10 += (double)fa1.x * (double)fb0.x; a10 += (double)fa1.y * (double)fb0.y;
      a11 += (double)fa1.x * (double)fb1.x; a11 += (double)fa1.y * (double)fb1.y;
    }
    __syncthreads();
  }

  // rows i0 = ti*32+ry, i1 = ti*32+ry+16; cols tj*32 + {cx, cx+16}
  bool p00 = (a00 / den[ry]      >= NMS_TH);
  bool p01 = (a01 / den[ry]      >= NMS_TH);
  bool p10 = (a10 / den[ry + 16] >= NMS_TH);
  bool p11 = (a11 / den[ry + 16] >= NMS_TH);
  unsigned long long bl0 = __ballot(p00);
  unsigned long long bh0 = __ballot(p01);
  unsigned long long bl1 = __ballot(p10);
  unsigned long long bh1 = __ballot(p11);
  int q = ry & 3;                       // 16-lane group within the wave
  if (cx == 0) {
    unsigned m0 = (unsigned)((bl0 >> (16 * q)) & 0xffffull) |
                  ((unsigned)((bh0 >> (16 * q)) & 0xffffull) << 16);
    unsigned m1 = (unsigned)((bl1 >> (16 * q)) & 0xffffull) |
                  ((unsigned)((bh1 >> (16 * q)) & 0xffffull) << 16);
    bits32[((size_t)s * NDET + ti * 32 + ry) * 16 + tj] = m0;
    bits32[((size_t)s * NDET + ti * 32 + ry + 16) * 16 + tj] = m1;
  }
}

// K4: greedy suppression (both sides) + combine. One block, 512 threads.
// Every lane of wave 0/1 holds the FULL 512-bit suppression mask in 8 u64
// registers (redundantly identical across lanes) -> active check is a
// register bit-test + scalar branch; suppressed rows cost ~8 instructions.
__global__ __launch_bounds__(512) void k4_greedy(
    const unsigned long long* __restrict__ bits,  // [2][512][8]
    const int* __restrict__ order,
    const double* __restrict__ u,
    float* __restrict__ outKeep) {
  __shared__ unsigned long long B[2 * NDET * 8];   // 64 KiB
  __shared__ unsigned char keepO[2 * NDET];        // by original index
  int t = threadIdx.x;

  // stage + mask j<=i (also kills garbage from never-written lower tiles)
  for (int e = t; e < 2 * NDET * 8; e += 512) {
    unsigned long long w = bits[e];
    int g = e & 7;
    int i = (e >> 3) & 511;
    int gi = i >> 6;
    if (g < gi) {
      w = 0ull;
    } else if (g == gi) {
      int li = i & 63;
      w = (li == 63) ? 0ull : (w & (~0ull << (li + 1)));
    }
    B[e] = w;
  }
  __syncthreads();

  int wv = t >> 6;
  int lane = t & 63;
  if (wv < 2) {
    int s = wv;
    const unsigned long long* Bside = B + (size_t)s * NDET * 8;
    unsigned long long S0 = 0, S1 = 0, S2 = 0, S3 = 0,
                       S4 = 0, S5 = 0, S6 = 0, S7 = 0;

#define GROUP(G, SG, ORS)                                              \
    for (int li = 0; li < 64; li++) {                                  \
      unsigned act = (unsigned)((SG >> li) & 1ull);                    \
      if (__builtin_amdgcn_readfirstlane(act) == 0) {                  \
        const unsigned long long* row = Bside + ((((G) << 6) | li) << 3); \
        ORS                                                            \
      }                                                                \
    }
    GROUP(0, S0, { S0 |= row[0]; S1 |= row[1]; S2 |= row[2]; S3 |= row[3];
                   S4 |= row[4]; S5 |= row[5]; S6 |= row[6]; S7 |= row[7]; })
    GROUP(1, S1, { S1 |= row[1]; S2 |= row[2]; S3 |= row[3];
                   S4 |= row[4]; S5 |= row[5]; S6 |= row[6]; S7 |= row[7]; })
    GROUP(2, S2, { S2 |= row[2]; S3 |= row[3];
                   S4 |= row[4]; S5 |= row[5]; S6 |= row[6]; S7 |= row[7]; })
    GROUP(3, S3, { S3 |= row[3];
                   S4 |= row[4]; S5 |= row[5]; S6 |= row[6]; S7 |= row[7]; })
    GROUP(4, S4, { S4 |= row[4]; S5 |= row[5]; S6 |= row[6]; S7 |= row[7]; })
    GROUP(5, S5, { S5 |= row[5]; S6 |= row[6]; S7 |= row[7]; })
    GROUP(6, S6, { S6 |= row[6]; S7 |= row[7]; })
    GROUP(7, S7, { S7 |= row[7]; })
#undef GROUP

    unsigned long long Sarr[8] = {S0, S1, S2, S3, S4, S5, S6, S7};
#pragma unroll
    for (int g = 0; g < 8; g++) {
      int c = (g << 6) | lane;                    // sorted position
      keepO[s * NDET + order[c]] =
          (unsigned char)(((Sarr[g] >> lane) & 1ull) ^ 1ull);
    }
  }
  __syncthreads();

  if (t < NDET) {
    bool valid = (u[t] > 0.0) && (u[NDET + t] > 0.0);
    outKeep[t] = (valid && keepO[t] && keepO[NDET + t]) ? 1.0f : 0.0f;
  }
}

extern "C" void kernel_launch(void* const* d_in, const int* in_sizes, int n_in,
                              void* d_out, int out_size, void* d_ws, size_t ws_size,
                              hipStream_t stream) {
  const float* left   = (const float*)d_in[0];
  const float* right  = (const float*)d_in[1];
  const float* scores = (const float*)d_in[2];
  const int*   labels = (const int*)d_in[3];
  float* out = (float*)d_out;

  char* ws = (char*)d_ws;
  double* u                = (double*)(ws + 0);
  int* order               = (int*)(ws + 8192);
  unsigned int* bits32     = (unsigned int*)(ws + 16384);
  unsigned long long* bits = (unsigned long long*)(ws + 16384);

  k1_gather_sigmoid<<<1024, 256, 0, stream>>>(left, right, labels, out, u);
  k2_sort<<<1, 512, 0, stream>>>(scores, order);
  k3_iou<<<272, 256, 0, stream>>>(out, u, order, bits32);
  k4_greedy<<<1, 512, 0, stream>>>(bits, order, u, out + PROBS_ELEMS);
}